// Round 1
// baseline (5482.607 us; speedup 1.0000x reference)
//
#include <hip/hip_runtime.h>

#define ND 64
#define ED 16
#define NN 50000
#define NE 800000
#define CIN 144   // 2*ND+ED
#define AGGD 80   // ND+ED
#define TE 32     // edges per head block
#define LSTR 33   // LDS row stride (TE+1, bank-conflict pad)

// ---- count in-degree (once; reused both layers) ----
__global__ __launch_bounds__(256) void count_kernel(const int* __restrict__ dst,
                                                    float* __restrict__ cnt) {
  int t = blockIdx.x * 256 + threadIdx.x;
  if (t < NE) atomicAdd(&cnt[dst[t]], 1.0f);
}

// ---- scatter: agg[dst] += concat(h[src], ef)  (float4 per thread, 4 atomics) ----
__global__ __launch_bounds__(256) void scatter_kernel(const float* __restrict__ h,
                                                      const int* __restrict__ src,
                                                      const int* __restrict__ dst,
                                                      const float* __restrict__ ef,
                                                      float* __restrict__ agg) {
  unsigned t = blockIdx.x * 256u + threadIdx.x;
  unsigned e = t / 20u;            // 20 float4 chunks per edge (16 from h, 4 from ef)
  unsigned f4 = t - e * 20u;
  int s = src[e], d = dst[e];
  float4 v;
  if (f4 < 16u) v = ((const float4*)(h + (size_t)s * ND))[f4];
  else          v = ((const float4*)(ef + (size_t)e * ED))[f4 - 16u];
  float* a = agg + (size_t)d * AGGD + f4 * 4u;
  atomicAdd(a + 0, v.x);
  atomicAdd(a + 1, v.y);
  atomicAdd(a + 2, v.z);
  atomicAdd(a + 3, v.w);
}

// ---- node conv: h_out = relu(concat(h, agg/max(cnt,1)) @ W + b), 4 nodes/block ----
__global__ __launch_bounds__(256) void node_kernel(const float* __restrict__ h,
                                                   const float* __restrict__ agg,
                                                   const float* __restrict__ cnt,
                                                   const float* __restrict__ W,   // [144][64]
                                                   const float* __restrict__ b,   // [64]
                                                   float* __restrict__ hout) {
  __shared__ float in[4][CIN];
  int j  = threadIdx.x & 63;
  int nl = threadIdx.x >> 6;
  int n  = blockIdx.x * 4 + nl;
  float inv = 1.0f / fmaxf(cnt[n], 1.0f);
  in[nl][j]      = h[(size_t)n * ND + j];
  in[nl][ND + j] = agg[(size_t)n * AGGD + j] * inv;
  if (j < ED) in[nl][2 * ND + j] = agg[(size_t)n * AGGD + ND + j] * inv;
  __syncthreads();
  float acc = b[j];
  #pragma unroll 4
  for (int i = 0; i < CIN; i++)
    acc = fmaf(in[nl][i], W[i * ND + j], acc);
  hout[(size_t)n * ND + j] = fmaxf(acc, 0.0f);
}

// ---- generic MLP layer on a 32-edge tile, transposed LDS [dim][TE(+pad)] ----
template<int NI, int NO, bool RELU>
__device__ __forceinline__ void mlp_layer(const float* __restrict__ W,
                                          const float* __restrict__ bias,
                                          const float* Zin, float* Zout, int t) {
  constexpr int JT = NO / 16;      // outputs per thread (256->16, 128->8, 64->4)
  int eg = t & 15;                 // edge pair: 2eg, 2eg+1
  int jg = t >> 4;                 // j block: jg*JT .. +JT-1
  const float* zp = Zin + 2 * eg;
  const float* wp = W + jg * JT;
  float acc0[JT], acc1[JT];
  #pragma unroll
  for (int k = 0; k < JT; k++) { float bb = bias[jg * JT + k]; acc0[k] = bb; acc1[k] = bb; }
  for (int i = 0; i < NI; i++) {
    float z0 = zp[i * LSTR];
    float z1 = zp[i * LSTR + 1];
    #pragma unroll
    for (int k = 0; k < JT; k++) {
      float w = wp[i * NO + k];
      acc0[k] = fmaf(z0, w, acc0[k]);
      acc1[k] = fmaf(z1, w, acc1[k]);
    }
  }
  #pragma unroll
  for (int k = 0; k < JT; k++) {
    int j = jg * JT + k;
    float a0 = acc0[k], a1 = acc1[k];
    if (RELU) { a0 = fmaxf(a0, 0.f); a1 = fmaxf(a1, 0.f); }
    Zout[j * LSTR + 2 * eg]     = a0;
    Zout[j * LSTR + 2 * eg + 1] = a1;
  }
}

// ---- fused edge head: gather pair -> 144->256->128->64->1 ----
__global__ __launch_bounds__(256) void head_kernel(const float* __restrict__ h,
    const int* __restrict__ src, const int* __restrict__ dst,
    const float* __restrict__ ef,
    const float* __restrict__ W1, const float* __restrict__ b1,
    const float* __restrict__ W2, const float* __restrict__ b2,
    const float* __restrict__ W3, const float* __restrict__ b3,
    const float* __restrict__ W4, const float* __restrict__ b4,
    float* __restrict__ out) {
  __shared__ float bufA[CIN * LSTR];   // pairT (144 rows) / z2T (128 rows)
  __shared__ float bufB[256 * LSTR];   // z1T (256 rows)  / z3T (64 rows)
  int t = threadIdx.x;
  int e0 = blockIdx.x * TE;
  for (int idx = t; idx < TE * CIN; idx += 256) {
    int el = idx / CIN;
    int i  = idx - el * CIN;
    int e  = e0 + el;
    float v;
    if (i < ND)          v = h[(size_t)src[e] * ND + i];
    else if (i < 2 * ND) v = h[(size_t)dst[e] * ND + (i - ND)];
    else                 v = ef[(size_t)e * ED + (i - 2 * ND)];
    bufA[i * LSTR + el] = v;
  }
  __syncthreads();
  mlp_layer<144, 256, true>(W1, b1, bufA, bufB, t); __syncthreads();
  mlp_layer<256, 128, true>(W2, b2, bufB, bufA, t); __syncthreads();
  mlp_layer<128, 64, true>(W3, b3, bufA, bufB, t);  __syncthreads();
  if (t < TE) {
    float acc = b4[0];
    #pragma unroll 8
    for (int i = 0; i < ND; i++) acc = fmaf(bufB[i * LSTR + t], W4[i], acc);
    out[e0 + t] = acc;
  }
}

extern "C" void kernel_launch(void* const* d_in, const int* in_sizes, int n_in,
                              void* d_out, int out_size, void* d_ws, size_t ws_size,
                              hipStream_t stream) {
  const float* x  = (const float*)d_in[0];
  const int*   ei = (const int*)d_in[1];
  const float* ef = (const float*)d_in[2];
  // d_in[3] = num_nodes (unused; compile-time NN)
  const float* cW = (const float*)d_in[4];
  const float* cb = (const float*)d_in[5];
  const float* W1 = (const float*)d_in[6];
  const float* b1 = (const float*)d_in[7];
  const float* W2 = (const float*)d_in[8];
  const float* b2 = (const float*)d_in[9];
  const float* W3 = (const float*)d_in[10];
  const float* b3 = (const float*)d_in[11];
  const float* W4 = (const float*)d_in[12];
  const float* b4 = (const float*)d_in[13];
  float* outp = (float*)d_out;

  const int* src = ei;
  const int* dst = ei + NE;

  float* h_a = (float*)d_ws;                 // [NN][64]
  float* h_b = h_a + (size_t)NN * ND;        // [NN][64]
  float* agg = h_b + (size_t)NN * ND;        // [NN][80]
  float* cnt = agg + (size_t)NN * AGGD;      // [NN]

  hipMemsetAsync(cnt, 0, NN * sizeof(float), stream);
  count_kernel<<<(NE + 255) / 256, 256, 0, stream>>>(dst, cnt);

  // layer 1 (input x)
  hipMemsetAsync(agg, 0, (size_t)NN * AGGD * sizeof(float), stream);
  scatter_kernel<<<NE * 20 / 256, 256, 0, stream>>>(x, src, dst, ef, agg);
  node_kernel<<<NN / 4, 256, 0, stream>>>(x, agg, cnt, cW, cb, h_a);

  // layer 2 (input h_a)
  hipMemsetAsync(agg, 0, (size_t)NN * AGGD * sizeof(float), stream);
  scatter_kernel<<<NE * 20 / 256, 256, 0, stream>>>(h_a, src, dst, ef, agg);
  node_kernel<<<NN / 4, 256, 0, stream>>>(h_a, agg, cnt, cW, cb, h_b);

  // edge head
  head_kernel<<<NE / TE, 256, 0, stream>>>(h_b, src, dst, ef,
                                           W1, b1, W2, b2, W3, b3, W4, b4, outp);
}

// Round 2
// 3749.472 us; speedup vs baseline: 1.4622x; 1.4622x over previous
//
#include <hip/hip_runtime.h>

#define ND 64
#define ED 16
#define NN 50000
#define NE 800000
#define CIN 144   // 2*ND+ED
#define AGGD 80   // ND+ED
#define TE 32     // edges per head block

typedef __attribute__((address_space(1))) const unsigned int guint;
typedef __attribute__((address_space(3))) unsigned int luint;

// ---- count in-degree (once; reused both layers) ----
__global__ __launch_bounds__(256) void count_kernel(const int* __restrict__ dst,
                                                    float* __restrict__ cnt) {
  int t = blockIdx.x * 256 + threadIdx.x;
  if (t < NE) atomicAdd(&cnt[dst[t]], 1.0f);
}

// ---- scatter: agg[dst] += concat(h[src], ef)  (float4 per thread, 4 atomics) ----
__global__ __launch_bounds__(256) void scatter_kernel(const float* __restrict__ h,
                                                      const int* __restrict__ src,
                                                      const int* __restrict__ dst,
                                                      const float* __restrict__ ef,
                                                      float* __restrict__ agg) {
  unsigned t = blockIdx.x * 256u + threadIdx.x;
  unsigned e = t / 20u;            // 20 float4 chunks per edge (16 from h, 4 from ef)
  unsigned f4 = t - e * 20u;
  int s = src[e], d = dst[e];
  float4 v;
  if (f4 < 16u) v = ((const float4*)(h + (size_t)s * ND))[f4];
  else          v = ((const float4*)(ef + (size_t)e * ED))[f4 - 16u];
  float* a = agg + (size_t)d * AGGD + f4 * 4u;
  atomicAdd(a + 0, v.x);
  atomicAdd(a + 1, v.y);
  atomicAdd(a + 2, v.z);
  atomicAdd(a + 3, v.w);
}

// ---- node conv: h_out = relu(concat(h, agg/max(cnt,1)) @ W + b), 4 nodes/block ----
__global__ __launch_bounds__(256) void node_kernel(const float* __restrict__ h,
                                                   const float* __restrict__ agg,
                                                   const float* __restrict__ cnt,
                                                   const float* __restrict__ W,   // [144][64]
                                                   const float* __restrict__ b,   // [64]
                                                   float* __restrict__ hout) {
  __shared__ float in[4][CIN];
  int j  = threadIdx.x & 63;
  int nl = threadIdx.x >> 6;
  int n  = blockIdx.x * 4 + nl;
  float inv = 1.0f / fmaxf(cnt[n], 1.0f);
  in[nl][j]      = h[(size_t)n * ND + j];
  in[nl][ND + j] = agg[(size_t)n * AGGD + j] * inv;
  if (j < ED) in[nl][2 * ND + j] = agg[(size_t)n * AGGD + ND + j] * inv;
  __syncthreads();
  float acc = b[j];
  #pragma unroll 4
  for (int i = 0; i < CIN; i++)
    acc = fmaf(in[nl][i], W[i * ND + j], acc);
  hout[(size_t)n * ND + j] = fmaxf(acc, 0.0f);
}

// ---- stage one 2048-float (8KB) weight chunk global->LDS (linear, per-wave 1KB segs) ----
__device__ __forceinline__ void stage_chunk(const float* g, float* l, int t) {
  int lid = t & 63, w = t >> 6;
  const float* gp = g + w * 512 + lid * 4;
  float* lp = l + w * 512;                  // wave-uniform base; HW adds lane*16B
  __builtin_amdgcn_global_load_lds((guint*)gp,         (luint*)lp,         16, 0, 0);
  __builtin_amdgcn_global_load_lds((guint*)(gp + 256), (luint*)(lp + 256), 16, 0, 0);
}

// ---- one MLP layer on a 32-edge tile; weights LDS-double-buffered in 8KB chunks ----
// thread: eg=t&7 -> edges 4eg..4eg+3 ; jg=t>>3 -> outputs jg*JT..+JT-1
template<int NI, int NO, bool RELU>
__device__ __forceinline__ void mlp_layer(const float* __restrict__ Wg,
                                          const float* __restrict__ bias,
                                          const float* Zin, float* Zout,
                                          float* wb0, float* wb1, int t) {
  constexpr int JT = NO / 32;        // 256->8, 128->4, 64->2
  constexpr int CR = 2048 / NO;      // k-rows per 8KB chunk: 8 / 16 / 32
  constexpr int NC = NI / CR;        // 18 / 16 / 4
  const int eg = t & 7;
  const int jg = t >> 3;
  float acc[4][JT];
  #pragma unroll
  for (int k = 0; k < JT; k++) {
    float bb = bias[jg * JT + k];
    acc[0][k] = bb; acc[1][k] = bb; acc[2][k] = bb; acc[3][k] = bb;
  }
  stage_chunk(Wg, wb0, t);
  __syncthreads();                   // drains vmcnt(0): chunk 0 ready
  for (int c = 0; c < NC; ++c) {
    float* wcur = (c & 1) ? wb1 : wb0;
    float* wnxt = (c & 1) ? wb0 : wb1;
    if (c + 1 < NC) stage_chunk(Wg + (size_t)(c + 1) * 2048, wnxt, t);
    #pragma unroll
    for (int ii = 0; ii < CR; ++ii) {
      const int i = c * CR + ii;
      float4 z = *(const float4*)(Zin + i * TE + 4 * eg);       // row-uniform: conflict-free
      const float* wr = wcur + ii * NO + jg * JT;               // row-uniform: conflict-free
      #pragma unroll
      for (int k = 0; k < JT; ++k) {
        float ww = wr[k];
        acc[0][k] = fmaf(z.x, ww, acc[0][k]);
        acc[1][k] = fmaf(z.y, ww, acc[1][k]);
        acc[2][k] = fmaf(z.z, ww, acc[2][k]);
        acc[3][k] = fmaf(z.w, ww, acc[3][k]);
      }
    }
    __syncthreads();                 // next chunk staged & visible; wcur free
  }
  #pragma unroll
  for (int k = 0; k < JT; ++k) {
    int j = jg * JT + k;
    float4 o = { acc[0][k], acc[1][k], acc[2][k], acc[3][k] };
    if (RELU) { o.x = fmaxf(o.x, 0.f); o.y = fmaxf(o.y, 0.f);
                o.z = fmaxf(o.z, 0.f); o.w = fmaxf(o.w, 0.f); }
    *(float4*)(Zout + j * TE + 4 * eg) = o;
  }
}

// ---- fused edge head: gather pair -> 144->256->128->64->1 ----
__global__ __launch_bounds__(256) void head_kernel(const float* __restrict__ h,
    const int* __restrict__ src, const int* __restrict__ dst,
    const float* __restrict__ ef,
    const float* __restrict__ W1, const float* __restrict__ b1,
    const float* __restrict__ W2, const float* __restrict__ b2,
    const float* __restrict__ W3, const float* __restrict__ b3,
    const float* __restrict__ W4, const float* __restrict__ b4,
    float* __restrict__ out) {
  __shared__ float zA[CIN * TE];     // 18KB: pairT; reused as z2T [128][32]
  __shared__ float zB[256 * TE];     // 32KB: z1T;   reused as z3T [64][32]
  __shared__ float wb[2][2048];      // 16KB: weight chunk double-buffer
  const int t = threadIdx.x;
  const int e0 = blockIdx.x * TE;

  // gather pairT: zA[i][el], float4-wide global reads
  {
    int el = t & 31, q = t >> 5;     // q = 0..7, 36 float4-chunks per edge
    int e = e0 + el;
    int s = src[e], d = dst[e];
    #pragma unroll
    for (int p = 0; p < 5; ++p) {
      int qq = q + p * 8;
      if (qq < 36) {
        float4 v;
        if (qq < 16)      v = ((const float4*)(h + (size_t)s * ND))[qq];
        else if (qq < 32) v = ((const float4*)(h + (size_t)d * ND))[qq - 16];
        else              v = ((const float4*)(ef + (size_t)e * ED))[qq - 32];
        zA[(4 * qq + 0) * TE + el] = v.x;
        zA[(4 * qq + 1) * TE + el] = v.y;
        zA[(4 * qq + 2) * TE + el] = v.z;
        zA[(4 * qq + 3) * TE + el] = v.w;
      }
    }
  }
  __syncthreads();

  mlp_layer<CIN, 256, true>(W1, b1, zA, zB, wb[0], wb[1], t);
  mlp_layer<256, 128, true>(W2, b2, zB, zA, wb[0], wb[1], t);
  mlp_layer<128,  64, true>(W3, b3, zA, zB, wb[0], wb[1], t);
  __syncthreads();

  if (t < TE) {                      // final 64->1 dot per edge
    float acc = b4[0];
    #pragma unroll 8
    for (int i = 0; i < ND; i++) acc = fmaf(zB[i * TE + t], W4[i], acc);
    out[e0 + t] = acc;
  }
}

extern "C" void kernel_launch(void* const* d_in, const int* in_sizes, int n_in,
                              void* d_out, int out_size, void* d_ws, size_t ws_size,
                              hipStream_t stream) {
  const float* x  = (const float*)d_in[0];
  const int*   ei = (const int*)d_in[1];
  const float* ef = (const float*)d_in[2];
  // d_in[3] = num_nodes (compile-time NN)
  const float* cW = (const float*)d_in[4];
  const float* cb = (const float*)d_in[5];
  const float* W1 = (const float*)d_in[6];
  const float* b1 = (const float*)d_in[7];
  const float* W2 = (const float*)d_in[8];
  const float* b2 = (const float*)d_in[9];
  const float* W3 = (const float*)d_in[10];
  const float* b3 = (const float*)d_in[11];
  const float* W4 = (const float*)d_in[12];
  const float* b4 = (const float*)d_in[13];
  float* outp = (float*)d_out;

  const int* src = ei;
  const int* dst = ei + NE;

  float* h_a = (float*)d_ws;                 // [NN][64]
  float* h_b = h_a + (size_t)NN * ND;        // [NN][64]
  float* agg = h_b + (size_t)NN * ND;        // [NN][80]
  float* cnt = agg + (size_t)NN * AGGD;      // [NN]

  hipMemsetAsync(cnt, 0, NN * sizeof(float), stream);
  count_kernel<<<(NE + 255) / 256, 256, 0, stream>>>(dst, cnt);

  // layer 1 (input x)
  hipMemsetAsync(agg, 0, (size_t)NN * AGGD * sizeof(float), stream);
  scatter_kernel<<<NE * 20 / 256, 256, 0, stream>>>(x, src, dst, ef, agg);
  node_kernel<<<NN / 4, 256, 0, stream>>>(x, agg, cnt, cW, cb, h_a);

  // layer 2 (input h_a)
  hipMemsetAsync(agg, 0, (size_t)NN * AGGD * sizeof(float), stream);
  scatter_kernel<<<NE * 20 / 256, 256, 0, stream>>>(h_a, src, dst, ef, agg);
  node_kernel<<<NN / 4, 256, 0, stream>>>(h_a, agg, cnt, cW, cb, h_b);

  // edge head
  head_kernel<<<NE / TE, 256, 0, stream>>>(h_b, src, dst, ef,
                                           W1, b1, W2, b2, W3, b3, W4, b4, outp);
}

// Round 3
// 2170.396 us; speedup vs baseline: 2.5261x; 1.7276x over previous
//
#include <hip/hip_runtime.h>

#define ND 64
#define ED 16
#define NN 50000
#define NE 800000
#define CIN 144   // 2*ND+ED
#define AGGD 80   // ND+ED
#define TE 32     // edges per head block

typedef __attribute__((address_space(1))) const unsigned int guint;
typedef __attribute__((address_space(3))) unsigned int luint;

// ---- in-degree (int), once ----
__global__ __launch_bounds__(256) void count_kernel(const int* __restrict__ dst,
                                                    int* __restrict__ dcnt) {
  int t = blockIdx.x * 256 + threadIdx.x;
  if (t < NE) atomicAdd(&dcnt[dst[t]], 1);
}

// ---- single-block exclusive scan: base = exscan(dcnt) ----
__global__ __launch_bounds__(1024) void scan_kernel(const int* __restrict__ dcnt,
                                                    int* __restrict__ base) {
  __shared__ int s[1024];
  __shared__ int carry;
  int t = threadIdx.x;
  if (t == 0) carry = 0;
  __syncthreads();
  for (int c = 0; c < (NN + 1023) / 1024; ++c) {
    int i = c * 1024 + t;
    int v = (i < NN) ? dcnt[i] : 0;
    s[t] = v;
    __syncthreads();
    #pragma unroll
    for (int d = 1; d < 1024; d <<= 1) {
      int add = (t >= d) ? s[t - d] : 0;
      __syncthreads();
      s[t] += add;
      __syncthreads();
    }
    if (i < NN) base[i] = carry + s[t] - v;
    int tot = s[1023];
    __syncthreads();
    if (t == 0) carry += tot;
    __syncthreads();
  }
}

// ---- counting-sort placement: edge -> its slot under dst ----
__global__ __launch_bounds__(256) void place_kernel(const int* __restrict__ src,
                                                    const int* __restrict__ dst,
                                                    const int* __restrict__ base,
                                                    int* __restrict__ fill,
                                                    int* __restrict__ sidx,
                                                    int* __restrict__ eidx) {
  int e = blockIdx.x * 256 + threadIdx.x;
  if (e < NE) {
    int d = dst[e];
    int slot = base[d] + atomicAdd(&fill[d], 1);
    sidx[slot] = src[e];
    eidx[slot] = e;
  }
}

// ---- per-node gather-sum: one wave per node, lane = feature dim ----
// agg[n][0:64] = sum_{e in in(n)} h[src[e]][:]
// WITH_EF: agg[n][64:80] = sum ef[e][:]   (layer-independent; written once)
template<bool WITH_EF>
__global__ __launch_bounds__(256) void gather_kernel(const float* __restrict__ h,
                                                     const int* __restrict__ sidx,
                                                     const int* __restrict__ eidx,
                                                     const float* __restrict__ ef,
                                                     const int* __restrict__ base,
                                                     const int* __restrict__ dcnt,
                                                     float* __restrict__ agg) {
  int wid  = (blockIdx.x * 256 + threadIdx.x) >> 6;
  int lane = threadIdx.x & 63;
  if (wid >= NN) return;
  int b0 = base[wid], deg = dcnt[wid];
  float acc = 0.f;
  int k = 0;
  for (; k + 2 <= deg; k += 2) {
    int s0 = sidx[b0 + k], s1 = sidx[b0 + k + 1];
    float a = h[(size_t)s0 * ND + lane];
    float b = h[(size_t)s1 * ND + lane];
    acc += a + b;
  }
  if (k < deg) acc += h[(size_t)sidx[b0 + k] * ND + lane];
  agg[(size_t)wid * AGGD + lane] = acc;
  if (WITH_EF) {
    int sub = lane >> 4, f = lane & 15;
    float ae = 0.f;
    for (int kk = sub; kk < deg; kk += 4)
      ae += ef[(size_t)eidx[b0 + kk] * ED + f];
    ae += __shfl_down(ae, 32);
    ae += __shfl_down(ae, 16);
    if (lane < 16) agg[(size_t)wid * AGGD + ND + lane] = ae;
  }
}

// ---- node conv: h_out = relu(concat(h, agg/max(cnt,1)) @ W + b), 4 nodes/block ----
__global__ __launch_bounds__(256) void node_kernel(const float* __restrict__ h,
                                                   const float* __restrict__ agg,
                                                   const int* __restrict__ dcnt,
                                                   const float* __restrict__ W,   // [144][64]
                                                   const float* __restrict__ b,   // [64]
                                                   float* __restrict__ hout) {
  __shared__ float in[4][CIN];
  int j  = threadIdx.x & 63;
  int nl = threadIdx.x >> 6;
  int n  = blockIdx.x * 4 + nl;
  float inv = 1.0f / fmaxf((float)dcnt[n], 1.0f);
  in[nl][j]      = h[(size_t)n * ND + j];
  in[nl][ND + j] = agg[(size_t)n * AGGD + j] * inv;
  if (j < ED) in[nl][2 * ND + j] = agg[(size_t)n * AGGD + ND + j] * inv;
  __syncthreads();
  float acc = b[j];
  #pragma unroll 4
  for (int i = 0; i < CIN; i++)
    acc = fmaf(in[nl][i], W[i * ND + j], acc);
  hout[(size_t)n * ND + j] = fmaxf(acc, 0.0f);
}

// ---- stage one 2048-float (8KB) weight chunk global->LDS ----
__device__ __forceinline__ void stage_chunk(const float* g, float* l, int t) {
  int lid = t & 63, w = t >> 6;
  const float* gp = g + w * 512 + lid * 4;
  float* lp = l + w * 512;                  // wave-uniform base; HW adds lane*16B
  __builtin_amdgcn_global_load_lds((guint*)gp,         (luint*)lp,         16, 0, 0);
  __builtin_amdgcn_global_load_lds((guint*)(gp + 256), (luint*)(lp + 256), 16, 0, 0);
}

// ---- one MLP layer on a 32-edge tile; weights LDS-double-buffered in 8KB chunks ----
template<int NI, int NO, bool RELU>
__device__ __forceinline__ void mlp_layer(const float* __restrict__ Wg,
                                          const float* __restrict__ bias,
                                          const float* Zin, float* Zout,
                                          float* wb0, float* wb1, int t) {
  constexpr int JT = NO / 32;        // 256->8, 128->4, 64->2
  constexpr int CR = 2048 / NO;      // k-rows per 8KB chunk
  constexpr int NC = NI / CR;
  const int eg = t & 7;
  const int jg = t >> 3;
  float acc[4][JT];
  #pragma unroll
  for (int k = 0; k < JT; k++) {
    float bb = bias[jg * JT + k];
    acc[0][k] = bb; acc[1][k] = bb; acc[2][k] = bb; acc[3][k] = bb;
  }
  stage_chunk(Wg, wb0, t);
  __syncthreads();
  for (int c = 0; c < NC; ++c) {
    float* wcur = (c & 1) ? wb1 : wb0;
    float* wnxt = (c & 1) ? wb0 : wb1;
    if (c + 1 < NC) stage_chunk(Wg + (size_t)(c + 1) * 2048, wnxt, t);
    #pragma unroll
    for (int ii = 0; ii < CR; ++ii) {
      const int i = c * CR + ii;
      float4 z = *(const float4*)(Zin + i * TE + 4 * eg);
      const float* wr = wcur + ii * NO + jg * JT;
      #pragma unroll
      for (int k = 0; k < JT; ++k) {
        float ww = wr[k];
        acc[0][k] = fmaf(z.x, ww, acc[0][k]);
        acc[1][k] = fmaf(z.y, ww, acc[1][k]);
        acc[2][k] = fmaf(z.z, ww, acc[2][k]);
        acc[3][k] = fmaf(z.w, ww, acc[3][k]);
      }
    }
    __syncthreads();
  }
  #pragma unroll
  for (int k = 0; k < JT; ++k) {
    int j = jg * JT + k;
    float4 o = { acc[0][k], acc[1][k], acc[2][k], acc[3][k] };
    if (RELU) { o.x = fmaxf(o.x, 0.f); o.y = fmaxf(o.y, 0.f);
                o.z = fmaxf(o.z, 0.f); o.w = fmaxf(o.w, 0.f); }
    *(float4*)(Zout + j * TE + 4 * eg) = o;
  }
}

// ---- fused edge head: gather pair -> 144->256->128->64->1 ----
__global__ __launch_bounds__(256) void head_kernel(const float* __restrict__ h,
    const int* __restrict__ src, const int* __restrict__ dst,
    const float* __restrict__ ef,
    const float* __restrict__ W1, const float* __restrict__ b1,
    const float* __restrict__ W2, const float* __restrict__ b2,
    const float* __restrict__ W3, const float* __restrict__ b3,
    const float* __restrict__ W4, const float* __restrict__ b4,
    float* __restrict__ out) {
  __shared__ float zA[CIN * TE];     // 18KB: pairT; reused as z2T [128][32]
  __shared__ float zB[256 * TE];     // 32KB: z1T;   reused as z3T [64][32]
  __shared__ float wb[2][2048];      // 16KB: weight double-buffer
  const int t = threadIdx.x;
  const int e0 = blockIdx.x * TE;

  {
    int el = t & 31, q = t >> 5;
    int e = e0 + el;
    int s = src[e], d = dst[e];
    #pragma unroll
    for (int p = 0; p < 5; ++p) {
      int qq = q + p * 8;
      if (qq < 36) {
        float4 v;
        if (qq < 16)      v = ((const float4*)(h + (size_t)s * ND))[qq];
        else if (qq < 32) v = ((const float4*)(h + (size_t)d * ND))[qq - 16];
        else              v = ((const float4*)(ef + (size_t)e * ED))[qq - 32];
        zA[(4 * qq + 0) * TE + el] = v.x;
        zA[(4 * qq + 1) * TE + el] = v.y;
        zA[(4 * qq + 2) * TE + el] = v.z;
        zA[(4 * qq + 3) * TE + el] = v.w;
      }
    }
  }
  __syncthreads();

  mlp_layer<CIN, 256, true>(W1, b1, zA, zB, wb[0], wb[1], t);
  mlp_layer<256, 128, true>(W2, b2, zB, zA, wb[0], wb[1], t);
  mlp_layer<128,  64, true>(W3, b3, zA, zB, wb[0], wb[1], t);
  __syncthreads();

  if (t < TE) {
    float acc = b4[0];
    #pragma unroll 8
    for (int i = 0; i < ND; i++) acc = fmaf(zB[i * TE + t], W4[i], acc);
    out[e0 + t] = acc;
  }
}

extern "C" void kernel_launch(void* const* d_in, const int* in_sizes, int n_in,
                              void* d_out, int out_size, void* d_ws, size_t ws_size,
                              hipStream_t stream) {
  const float* x  = (const float*)d_in[0];
  const int*   ei = (const int*)d_in[1];
  const float* ef = (const float*)d_in[2];
  const float* cW = (const float*)d_in[4];
  const float* cb = (const float*)d_in[5];
  const float* W1 = (const float*)d_in[6];
  const float* b1 = (const float*)d_in[7];
  const float* W2 = (const float*)d_in[8];
  const float* b2 = (const float*)d_in[9];
  const float* W3 = (const float*)d_in[10];
  const float* b3 = (const float*)d_in[11];
  const float* W4 = (const float*)d_in[12];
  const float* b4 = (const float*)d_in[13];
  float* outp = (float*)d_out;

  const int* src = ei;
  const int* dst = ei + NE;

  float* h_a  = (float*)d_ws;                 // [NN][64]
  float* h_b  = h_a + (size_t)NN * ND;        // [NN][64]
  float* agg  = h_b + (size_t)NN * ND;        // [NN][80]
  int*   dcnt = (int*)(agg + (size_t)NN * AGGD);  // [NN]
  int*   base = dcnt + NN;                    // [NN]
  int*   fill = base + NN;                    // [NN]
  int*   sidx = fill + NN;                    // [NE]
  int*   eidx = sidx + NE;                    // [NE]

  // ---- CSR build (once; reused both layers) ----
  hipMemsetAsync(dcnt, 0, 2 * NN * sizeof(int), stream);  // dcnt + (base later overwritten)
  hipMemsetAsync(fill, 0, NN * sizeof(int), stream);
  count_kernel<<<(NE + 255) / 256, 256, 0, stream>>>(dst, dcnt);
  scan_kernel<<<1, 1024, 0, stream>>>(dcnt, base);
  place_kernel<<<(NE + 255) / 256, 256, 0, stream>>>(src, dst, base, fill, sidx, eidx);

  // ---- layer 1 (input x) ----
  gather_kernel<true><<<NN / 4, 256, 0, stream>>>(x, sidx, eidx, ef, base, dcnt, agg);
  node_kernel<<<NN / 4, 256, 0, stream>>>(x, agg, dcnt, cW, cb, h_a);

  // ---- layer 2 (input h_a); ef columns of agg persist from layer 1 ----
  gather_kernel<false><<<NN / 4, 256, 0, stream>>>(h_a, sidx, eidx, ef, base, dcnt, agg);
  node_kernel<<<NN / 4, 256, 0, stream>>>(h_a, agg, dcnt, cW, cb, h_b);

  // ---- edge head ----
  head_kernel<<<NE / TE, 256, 0, stream>>>(h_b, src, dst, ef,
                                           W1, b1, W2, b2, W3, b3, W4, b4, outp);
}

// Round 4
// 1405.425 us; speedup vs baseline: 3.9010x; 1.5443x over previous
//
#include <hip/hip_runtime.h>
#include <hip/hip_bf16.h>

#define ND 64
#define ED 16
#define NN 50000
#define NE 800000
#define CIN 144   // 2*ND+ED
#define AGGD 80   // ND+ED
#define TE 32     // edges per head block

typedef __attribute__((ext_vector_type(8))) short short8;
typedef __attribute__((ext_vector_type(4))) float f32x4;
typedef __attribute__((ext_vector_type(4))) unsigned int uint4v;

union FragU { uint4v u; short8 s; };

// ================= graph pipeline (unchanged from R3) =================

__global__ __launch_bounds__(256) void count_kernel(const int* __restrict__ dst,
                                                    int* __restrict__ dcnt) {
  int t = blockIdx.x * 256 + threadIdx.x;
  if (t < NE) atomicAdd(&dcnt[dst[t]], 1);
}

__global__ __launch_bounds__(1024) void scan_kernel(const int* __restrict__ dcnt,
                                                    int* __restrict__ base) {
  __shared__ int s[1024];
  __shared__ int carry;
  int t = threadIdx.x;
  if (t == 0) carry = 0;
  __syncthreads();
  for (int c = 0; c < (NN + 1023) / 1024; ++c) {
    int i = c * 1024 + t;
    int v = (i < NN) ? dcnt[i] : 0;
    s[t] = v;
    __syncthreads();
    #pragma unroll
    for (int d = 1; d < 1024; d <<= 1) {
      int add = (t >= d) ? s[t - d] : 0;
      __syncthreads();
      s[t] += add;
      __syncthreads();
    }
    if (i < NN) base[i] = carry + s[t] - v;
    int tot = s[1023];
    __syncthreads();
    if (t == 0) carry += tot;
    __syncthreads();
  }
}

__global__ __launch_bounds__(256) void place_kernel(const int* __restrict__ src,
                                                    const int* __restrict__ dst,
                                                    const int* __restrict__ base,
                                                    int* __restrict__ fill,
                                                    int* __restrict__ sidx,
                                                    int* __restrict__ eidx) {
  int e = blockIdx.x * 256 + threadIdx.x;
  if (e < NE) {
    int d = dst[e];
    int slot = base[d] + atomicAdd(&fill[d], 1);
    sidx[slot] = src[e];
    eidx[slot] = e;
  }
}

template<bool WITH_EF>
__global__ __launch_bounds__(256) void gather_kernel(const float* __restrict__ h,
                                                     const int* __restrict__ sidx,
                                                     const int* __restrict__ eidx,
                                                     const float* __restrict__ ef,
                                                     const int* __restrict__ base,
                                                     const int* __restrict__ dcnt,
                                                     float* __restrict__ agg) {
  int wid  = (blockIdx.x * 256 + threadIdx.x) >> 6;
  int lane = threadIdx.x & 63;
  if (wid >= NN) return;
  int b0 = base[wid], deg = dcnt[wid];
  float acc = 0.f;
  int k = 0;
  for (; k + 2 <= deg; k += 2) {
    int s0 = sidx[b0 + k], s1 = sidx[b0 + k + 1];
    float a = h[(size_t)s0 * ND + lane];
    float b = h[(size_t)s1 * ND + lane];
    acc += a + b;
  }
  if (k < deg) acc += h[(size_t)sidx[b0 + k] * ND + lane];
  agg[(size_t)wid * AGGD + lane] = acc;
  if (WITH_EF) {
    int sub = lane >> 4, f = lane & 15;
    float ae = 0.f;
    for (int kk = sub; kk < deg; kk += 4)
      ae += ef[(size_t)eidx[b0 + kk] * ED + f];
    ae += __shfl_down(ae, 32);
    ae += __shfl_down(ae, 16);
    if (lane < 16) agg[(size_t)wid * AGGD + ND + lane] = ae;
  }
}

__global__ __launch_bounds__(256) void node_kernel(const float* __restrict__ h,
                                                   const float* __restrict__ agg,
                                                   const int* __restrict__ dcnt,
                                                   const float* __restrict__ W,
                                                   const float* __restrict__ b,
                                                   float* __restrict__ hout) {
  __shared__ float in[4][CIN];
  int j  = threadIdx.x & 63;
  int nl = threadIdx.x >> 6;
  int n  = blockIdx.x * 4 + nl;
  float inv = 1.0f / fmaxf((float)dcnt[n], 1.0f);
  in[nl][j]      = h[(size_t)n * ND + j];
  in[nl][ND + j] = agg[(size_t)n * AGGD + j] * inv;
  if (j < ED) in[nl][2 * ND + j] = agg[(size_t)n * AGGD + ND + j] * inv;
  __syncthreads();
  float acc = b[j];
  #pragma unroll 4
  for (int i = 0; i < CIN; i++)
    acc = fmaf(in[nl][i], W[i * ND + j], acc);
  hout[(size_t)n * ND + j] = fmaxf(acc, 0.0f);
}

// ================= weight prep: 3-split bf16, tiled for MFMA B-frags =========
// WT layout: [ct][kg][r][i] ushort ; ct = col-tile (16 cols), kg = 8-k group,
// r = col-in-tile, i = k-in-group. One (ct,kstep32) block = 1024 B, lane off = l*16B.
// k' in [0,3KP): p = k'/KP -> {Wh, Wh, Wl}; matches A' = [Ah | Al | Ah].
template<int K, int KP, int NO>
__global__ __launch_bounds__(256) void prep_kernel(const float* __restrict__ W,
                                                   unsigned short* __restrict__ WT) {
  constexpr int NKG = 3 * KP / 8;
  int idx = blockIdx.x * 256 + threadIdx.x;
  if (idx >= NO * 3 * KP) return;
  int i = idx & 7;
  int r = (idx >> 3) & 15;
  int rest = idx >> 7;              // ct*NKG + kg
  int kg = rest % NKG, ct = rest / NKG;
  int kp = kg * 8 + i;
  int p = kp / KP, k = kp - p * KP;
  int n = ct * 16 + r;
  float wv = (k < K) ? W[k * NO + n] : 0.f;
  unsigned u = __float_as_uint(wv);
  unsigned hi = (u + 0x7fffu + ((u >> 16) & 1u)) >> 16;   // bf16 RNE
  unsigned outb;
  if (p < 2) outb = hi;
  else {
    float lo = wv - __uint_as_float(hi << 16);
    unsigned ul = __float_as_uint(lo);
    outb = (ul + 0x7fffu + ((ul >> 16) & 1u)) >> 16;
  }
  WT[idx] = (unsigned short)outb;
}

// ================= MFMA head =================

__device__ __forceinline__ unsigned packbf(float a, float b) {
  __hip_bfloat162 h = __float22bfloat162_rn(float2{a, b});
  unsigned r;
  __builtin_memcpy(&r, &h, 4);
  return r;                          // low16 = bf16(a), high16 = bf16(b)
}
__device__ __forceinline__ float lo16f(unsigned u) { return __uint_as_float(u << 16); }
__device__ __forceinline__ float hi16f(unsigned u) { return __uint_as_float(u & 0xffff0000u); }

template<bool LO>
__device__ __forceinline__ short8 build_afrag(const float* ap) {
  float4 a0 = *(const float4*)ap;
  float4 a1 = *(const float4*)(ap + 4);
  unsigned h0 = packbf(a0.x, a0.y), h1 = packbf(a0.z, a0.w);
  unsigned h2 = packbf(a1.x, a1.y), h3 = packbf(a1.z, a1.w);
  FragU f;
  if (!LO) {
    f.u = uint4v{h0, h1, h2, h3};
  } else {
    f.u[0] = packbf(a0.x - lo16f(h0), a0.y - hi16f(h0));
    f.u[1] = packbf(a0.z - lo16f(h1), a0.w - hi16f(h1));
    f.u[2] = packbf(a1.x - lo16f(h2), a1.y - hi16f(h2));
    f.u[3] = packbf(a1.z - lo16f(h3), a1.w - hi16f(h3));
  }
  return f.s;
}

// One GEMM layer: z_out[32][NO] = relu(z_in[32][KP(-pad)] @ W + b)
// 4 waves: rb = w&1 (16 rows), ct range = (w>>1)*TPW..+TPW. Barrier-free k-loop;
// B-frags direct from L2 (1-deep register prefetch); A-frags f32->bf16 split on the fly.
template<int KP, int NO, int SIN, int SOUT>
__device__ __forceinline__ void mfma_layer(const float* __restrict__ zin,
                                           float* __restrict__ zout,
                                           const unsigned short* __restrict__ WT,
                                           const float* __restrict__ bias,
                                           int w, int l) {
  constexpr int NKS  = 3 * KP / 32;  // 15 / 24 / 12
  constexpr int TPW  = NO / 32;      // 8 / 4 / 2
  constexpr int KS_P = KP / 32;
  const int rb  = w & 1;
  const int ctb = (w >> 1) * TPW;
  const int lr = l & 15, lk = l >> 4;
  const int arow = rb * 16 + lr;
  const float* abase = zin + arow * SIN + lk * 8;

  float bv[TPW];
  #pragma unroll
  for (int j = 0; j < TPW; ++j) bv[j] = bias[(ctb + j) * 16 + lr];

  f32x4 acc[TPW];
  #pragma unroll
  for (int j = 0; j < TPW; ++j) acc[j] = f32x4{0.f, 0.f, 0.f, 0.f};

  const unsigned short* wtl = WT + l * 8;
  FragU cur[TPW], nxt[TPW];
  #pragma unroll
  for (int j = 0; j < TPW; ++j)
    cur[j].u = *(const uint4v*)(wtl + (ctb + j) * NKS * 512);

  #pragma unroll
  for (int ks = 0; ks < NKS; ++ks) {
    if (ks + 1 < NKS) {
      #pragma unroll
      for (int j = 0; j < TPW; ++j)
        nxt[j].u = *(const uint4v*)(wtl + ((ctb + j) * NKS + ks + 1) * 512);
    }
    const int kk = ks % KS_P;        // compile-time after unroll
    short8 af = ((ks / KS_P) == 1) ? build_afrag<true>(abase + kk * 32)
                                   : build_afrag<false>(abase + kk * 32);
    #pragma unroll
    for (int j = 0; j < TPW; ++j)
      acc[j] = __builtin_amdgcn_mfma_f32_16x16x32_bf16(af, cur[j].s, acc[j], 0, 0, 0);
    if (ks + 1 < NKS) {
      #pragma unroll
      for (int j = 0; j < TPW; ++j) cur[j] = nxt[j];
    }
  }

  // C layout (m89): col = lane&15, row = (lane>>4)*4 + q
  #pragma unroll
  for (int j = 0; j < TPW; ++j) {
    const int col = (ctb + j) * 16 + lr;
    #pragma unroll
    for (int q = 0; q < 4; ++q) {
      const int row = rb * 16 + lk * 4 + q;
      zout[row * SOUT + col] = fmaxf(acc[j][q] + bv[j], 0.f);
    }
  }
}

__global__ __launch_bounds__(256, 2) void head_kernel(
    const float* __restrict__ h,
    const int* __restrict__ src, const int* __restrict__ dst,
    const float* __restrict__ ef,
    const unsigned short* __restrict__ WT1, const unsigned short* __restrict__ WT2,
    const unsigned short* __restrict__ WT3,
    const float* __restrict__ b1, const float* __restrict__ b2,
    const float* __restrict__ b3,
    const float* __restrict__ W4, const float* __restrict__ b4,
    float* __restrict__ out) {
  __shared__ float R0[TE * 164];     // pair [32][164] / z2 [32][132]
  __shared__ float R1[TE * 260];     // z1 [32][260]  / z3 [32][68]
  const int t = threadIdx.x;
  const int e0 = blockIdx.x * TE;
  const int w = t >> 6, l = t & 63;

  { // gather pair rows: [el][0:144) = [h_src | h_dst | ef], zero-pad [144,160)
    int el = t & 31, q = t >> 5;
    int e = e0 + el;
    int s = src[e], d = dst[e];
    float* prow = R0 + el * 164;
    #pragma unroll
    for (int p5 = 0; p5 < 5; ++p5) {
      int qq = q + p5 * 8;
      float4 v = {0.f, 0.f, 0.f, 0.f};
      if (qq < 16)      v = ((const float4*)(h + (size_t)s * ND))[qq];
      else if (qq < 32) v = ((const float4*)(h + (size_t)d * ND))[qq - 16];
      else if (qq < 36) v = ((const float4*)(ef + (size_t)e * ED))[qq - 32];
      *(float4*)(prow + qq * 4) = v;
    }
  }
  __syncthreads();
  mfma_layer<160, 256, 164, 260>(R0, R1, WT1, b1, w, l);
  __syncthreads();
  mfma_layer<256, 128, 260, 132>(R1, R0, WT2, b2, w, l);
  __syncthreads();
  mfma_layer<128,  64, 132,  68>(R0, R1, WT3, b3, w, l);
  __syncthreads();
  if (t < TE) {
    const float* zr = R1 + t * 68;
    float acc = b4[0];
    #pragma unroll
    for (int q = 0; q < 16; ++q) {
      float4 z  = *(const float4*)(zr + q * 4);
      float4 wv = *(const float4*)(W4 + q * 4);
      acc = fmaf(z.x, wv.x, acc); acc = fmaf(z.y, wv.y, acc);
      acc = fmaf(z.z, wv.z, acc); acc = fmaf(z.w, wv.w, acc);
    }
    out[e0 + t] = acc;
  }
}

// ================= launch =================

extern "C" void kernel_launch(void* const* d_in, const int* in_sizes, int n_in,
                              void* d_out, int out_size, void* d_ws, size_t ws_size,
                              hipStream_t stream) {
  const float* x  = (const float*)d_in[0];
  const int*   ei = (const int*)d_in[1];
  const float* ef = (const float*)d_in[2];
  const float* cW = (const float*)d_in[4];
  const float* cb = (const float*)d_in[5];
  const float* W1 = (const float*)d_in[6];
  const float* b1 = (const float*)d_in[7];
  const float* W2 = (const float*)d_in[8];
  const float* b2 = (const float*)d_in[9];
  const float* W3 = (const float*)d_in[10];
  const float* b3 = (const float*)d_in[11];
  const float* W4 = (const float*)d_in[12];
  const float* b4 = (const float*)d_in[13];
  float* outp = (float*)d_out;

  const int* src = ei;
  const int* dst = ei + NE;

  float* h_a  = (float*)d_ws;                     // [NN][64]
  float* h_b  = h_a + (size_t)NN * ND;            // [NN][64]
  float* agg  = h_b + (size_t)NN * ND;            // [NN][80]
  int*   dcnt = (int*)(agg + (size_t)NN * AGGD);  // [NN]
  int*   base = dcnt + NN;                        // [NN]
  int*   fill = base + NN;                        // [NN]
  int*   sidx = fill + NN;                        // [NE]
  int*   eidx = sidx + NE;                        // [NE]
  unsigned short* WT1 =
      (unsigned short*)(((uintptr_t)(eidx + NE) + 63) & ~(uintptr_t)63);
  unsigned short* WT2 = WT1 + 160 * 3 * 256;      // 122880
  unsigned short* WT3 = WT2 + 256 * 3 * 128;      // 98304; WT3: 24576

  // ---- weight prep (3-split bf16, tiled) ----
  prep_kernel<144, 160, 256><<<480, 256, 0, stream>>>(W1, WT1);
  prep_kernel<256, 256, 128><<<384, 256, 0, stream>>>(W2, WT2);
  prep_kernel<128, 128,  64><<< 96, 256, 0, stream>>>(W3, WT3);

  // ---- CSR build (once; reused both layers) ----
  hipMemsetAsync(dcnt, 0, NN * sizeof(int), stream);
  hipMemsetAsync(fill, 0, NN * sizeof(int), stream);
  count_kernel<<<(NE + 255) / 256, 256, 0, stream>>>(dst, dcnt);
  scan_kernel<<<1, 1024, 0, stream>>>(dcnt, base);
  place_kernel<<<(NE + 255) / 256, 256, 0, stream>>>(src, dst, base, fill, sidx, eidx);

  // ---- layer 1 (input x) ----
  gather_kernel<true><<<NN / 4, 256, 0, stream>>>(x, sidx, eidx, ef, base, dcnt, agg);
  node_kernel<<<NN / 4, 256, 0, stream>>>(x, agg, dcnt, cW, cb, h_a);

  // ---- layer 2 (input h_a); ef columns of agg persist ----
  gather_kernel<false><<<NN / 4, 256, 0, stream>>>(h_a, sidx, eidx, ef, base, dcnt, agg);
  node_kernel<<<NN / 4, 256, 0, stream>>>(h_a, agg, dcnt, cW, cb, h_b);

  // ---- edge head (MFMA) ----
  head_kernel<<<NE / TE, 256, 0, stream>>>(h_b, src, dst, ef,
                                           WT1, WT2, WT3, b1, b2, b3, W4, b4, outp);
}

// Round 5
// 1074.505 us; speedup vs baseline: 5.1024x; 1.3080x over previous
//
#include <hip/hip_runtime.h>

#define ND 64
#define ED 16
#define NN 50000
#define NE 800000
#define CIN 144   // 2*ND+ED
#define AGGD 80   // ND+ED
#define TE 32     // edges per head block

typedef __attribute__((ext_vector_type(8))) short short8;
typedef __attribute__((ext_vector_type(4))) float f32x4;
typedef __attribute__((ext_vector_type(4))) unsigned int uint4v;
typedef __attribute__((ext_vector_type(4))) unsigned short ushort4v;

union FragU { uint4v u; short8 s; };

__device__ __forceinline__ unsigned bf16rne(float v) {
  unsigned u = __float_as_uint(v);
  return (u + 0x7fffu + ((u >> 16) & 1u)) >> 16;
}

// ================= graph pipeline (unchanged) =================

__global__ __launch_bounds__(256) void count_kernel(const int* __restrict__ dst,
                                                    int* __restrict__ dcnt) {
  int t = blockIdx.x * 256 + threadIdx.x;
  if (t < NE) atomicAdd(&dcnt[dst[t]], 1);
}

__global__ __launch_bounds__(1024) void scan_kernel(const int* __restrict__ dcnt,
                                                    int* __restrict__ base) {
  __shared__ int s[1024];
  __shared__ int carry;
  int t = threadIdx.x;
  if (t == 0) carry = 0;
  __syncthreads();
  for (int c = 0; c < (NN + 1023) / 1024; ++c) {
    int i = c * 1024 + t;
    int v = (i < NN) ? dcnt[i] : 0;
    s[t] = v;
    __syncthreads();
    #pragma unroll
    for (int d = 1; d < 1024; d <<= 1) {
      int add = (t >= d) ? s[t - d] : 0;
      __syncthreads();
      s[t] += add;
      __syncthreads();
    }
    if (i < NN) base[i] = carry + s[t] - v;
    int tot = s[1023];
    __syncthreads();
    if (t == 0) carry += tot;
    __syncthreads();
  }
}

__global__ __launch_bounds__(256) void place_kernel(const int* __restrict__ src,
                                                    const int* __restrict__ dst,
                                                    const int* __restrict__ base,
                                                    int* __restrict__ fill,
                                                    int* __restrict__ sidx,
                                                    int* __restrict__ eidx) {
  int e = blockIdx.x * 256 + threadIdx.x;
  if (e < NE) {
    int d = dst[e];
    int slot = base[d] + atomicAdd(&fill[d], 1);
    sidx[slot] = src[e];
    eidx[slot] = e;
  }
}

template<bool WITH_EF>
__global__ __launch_bounds__(256) void gather_kernel(const float* __restrict__ h,
                                                     const int* __restrict__ sidx,
                                                     const int* __restrict__ eidx,
                                                     const float* __restrict__ ef,
                                                     const int* __restrict__ base,
                                                     const int* __restrict__ dcnt,
                                                     float* __restrict__ agg) {
  int wid  = (blockIdx.x * 256 + threadIdx.x) >> 6;
  int lane = threadIdx.x & 63;
  if (wid >= NN) return;
  int b0 = base[wid], deg = dcnt[wid];
  float acc = 0.f;
  int k = 0;
  for (; k + 2 <= deg; k += 2) {
    int s0 = sidx[b0 + k], s1 = sidx[b0 + k + 1];
    float a = h[(size_t)s0 * ND + lane];
    float b = h[(size_t)s1 * ND + lane];
    acc += a + b;
  }
  if (k < deg) acc += h[(size_t)sidx[b0 + k] * ND + lane];
  agg[(size_t)wid * AGGD + lane] = acc;
  if (WITH_EF) {
    int sub = lane >> 4, f = lane & 15;
    float ae = 0.f;
    for (int kk = sub; kk < deg; kk += 4)
      ae += ef[(size_t)eidx[b0 + kk] * ED + f];
    ae += __shfl_down(ae, 32);
    ae += __shfl_down(ae, 16);
    if (lane < 16) agg[(size_t)wid * AGGD + ND + lane] = ae;
  }
}

__global__ __launch_bounds__(256) void node_kernel(const float* __restrict__ h,
                                                   const float* __restrict__ agg,
                                                   const int* __restrict__ dcnt,
                                                   const float* __restrict__ W,
                                                   const float* __restrict__ b,
                                                   float* __restrict__ hout) {
  __shared__ float in[4][CIN];
  int j  = threadIdx.x & 63;
  int nl = threadIdx.x >> 6;
  int n  = blockIdx.x * 4 + nl;
  float inv = 1.0f / fmaxf((float)dcnt[n], 1.0f);
  in[nl][j]      = h[(size_t)n * ND + j];
  in[nl][ND + j] = agg[(size_t)n * AGGD + j] * inv;
  if (j < ED) in[nl][2 * ND + j] = agg[(size_t)n * AGGD + ND + j] * inv;
  __syncthreads();
  float acc = b[j];
  #pragma unroll 4
  for (int i = 0; i < CIN; i++)
    acc = fmaf(in[nl][i], W[i * ND + j], acc);
  hout[(size_t)n * ND + j] = fmaxf(acc, 0.0f);
}

// ============ weight prep: separate Wh / Wl bf16 arrays, MFMA-tiled ==========
// Layout: idx = (ct*KS + ks)*512 + lk*128 + lr*8 + i  -> element
//         (k = ks*32 + lk*8 + i , n = ct*16 + lr).  Lane l=(lk*16+lr) reads
//         16B at block + l*8 ushorts -> exact B-frag for mfma_16x16x32_bf16.
template<int K, int KP, int NO, bool LO>
__global__ __launch_bounds__(256) void prep_kernel(const float* __restrict__ W,
                                                   unsigned short* __restrict__ WT) {
  constexpr int KS = KP / 32;
  int idx = blockIdx.x * 256 + threadIdx.x;
  if (idx >= KP * NO) return;
  int i  = idx & 7;
  int lr = (idx >> 3) & 15;
  int lk = (idx >> 7) & 3;
  int rest = idx >> 9;
  int ks = rest % KS, ct = rest / KS;
  int k = ks * 32 + lk * 8 + i;
  int n = ct * 16 + lr;
  float wv = (k < K) ? W[k * NO + n] : 0.f;
  unsigned hi = bf16rne(wv);
  unsigned outb = hi;
  if (LO) {
    float lo = wv - __uint_as_float(hi << 16);
    outb = bf16rne(lo);
  }
  WT[idx] = (unsigned short)outb;
}

// ================= MFMA head =================
// One layer: z_out[32][NO] = relu(z_in[32][KP] @ W + b).
// Input/output activations live in LDS as bf16 hi/lo planes (split precomputed).
// 4 waves, each owns CTW disjoint col-tiles and BOTH 16-row blocks.
// Per kstep: load Wh,Wl frags (L2), 4x ds_read_b128 A-frags, 6*CTW MFMAs:
//   acc += Ah*Wh + Al*Wh + Ah*Wl   (drop Al*Wl, ~2^-18 rel)
template<int KP, int NO, int SIN, int SOUT, int CTW, bool F32OUT>
__device__ __forceinline__ void mfma_layer(
    const unsigned short* __restrict__ zh, const unsigned short* __restrict__ zl,
    unsigned short* __restrict__ oh, unsigned short* __restrict__ ol,
    float* __restrict__ of,
    const unsigned short* __restrict__ WTh, const unsigned short* __restrict__ WTl,
    const float* __restrict__ bias, int w, int l) {
  constexpr int KS = KP / 32;
  const int lr = l & 15, lk = l >> 4;
  const int ct0 = w * CTW;
  const unsigned short* a0h = zh + lr * SIN + lk * 8;
  const unsigned short* a1h = a0h + 16 * SIN;
  const unsigned short* a0l = zl + lr * SIN + lk * 8;
  const unsigned short* a1l = a0l + 16 * SIN;
  const unsigned short* wth = WTh + (size_t)(ct0 * KS) * 512 + l * 8;
  const unsigned short* wtl = WTl + (size_t)(ct0 * KS) * 512 + l * 8;

  f32x4 acc[CTW][2];
  #pragma unroll
  for (int j = 0; j < CTW; ++j) {
    acc[j][0] = f32x4{0.f, 0.f, 0.f, 0.f};
    acc[j][1] = f32x4{0.f, 0.f, 0.f, 0.f};
  }

  FragU whf[CTW], wlf[CTW], nwh[CTW], nwl[CTW];
  #pragma unroll
  for (int j = 0; j < CTW; ++j) {
    whf[j].u = *(const uint4v*)(wth + j * KS * 512);
    wlf[j].u = *(const uint4v*)(wtl + j * KS * 512);
  }

  #pragma unroll
  for (int ks = 0; ks < KS; ++ks) {
    FragU A0h, A1h, A0l, A1l;
    A0h.s = *(const short8*)(a0h + ks * 32);
    A1h.s = *(const short8*)(a1h + ks * 32);
    A0l.s = *(const short8*)(a0l + ks * 32);
    A1l.s = *(const short8*)(a1l + ks * 32);
    if (ks + 1 < KS) {
      #pragma unroll
      for (int j = 0; j < CTW; ++j) {
        nwh[j].u = *(const uint4v*)(wth + (j * KS + ks + 1) * 512);
        nwl[j].u = *(const uint4v*)(wtl + (j * KS + ks + 1) * 512);
      }
    }
    #pragma unroll
    for (int j = 0; j < CTW; ++j) {
      acc[j][0] = __builtin_amdgcn_mfma_f32_16x16x32_bf16(A0h.s, whf[j].s, acc[j][0], 0, 0, 0);
      acc[j][1] = __builtin_amdgcn_mfma_f32_16x16x32_bf16(A1h.s, whf[j].s, acc[j][1], 0, 0, 0);
      acc[j][0] = __builtin_amdgcn_mfma_f32_16x16x32_bf16(A0l.s, whf[j].s, acc[j][0], 0, 0, 0);
      acc[j][1] = __builtin_amdgcn_mfma_f32_16x16x32_bf16(A1l.s, whf[j].s, acc[j][1], 0, 0, 0);
      acc[j][0] = __builtin_amdgcn_mfma_f32_16x16x32_bf16(A0h.s, wlf[j].s, acc[j][0], 0, 0, 0);
      acc[j][1] = __builtin_amdgcn_mfma_f32_16x16x32_bf16(A1h.s, wlf[j].s, acc[j][1], 0, 0, 0);
    }
    if (ks + 1 < KS) {
      #pragma unroll
      for (int j = 0; j < CTW; ++j) { whf[j] = nwh[j]; wlf[j] = nwl[j]; }
    }
  }

  // C layout (m89): col = lane&15, row = (lane>>4)*4 + q  (+ rb*16)
  #pragma unroll
  for (int j = 0; j < CTW; ++j) {
    const int col = (ct0 + j) * 16 + lr;
    const float bb = bias[col];
    #pragma unroll
    for (int rb = 0; rb < 2; ++rb) {
      #pragma unroll
      for (int q = 0; q < 4; ++q) {
        const int row = rb * 16 + lk * 4 + q;
        float v = fmaxf(acc[j][rb][q] + bb, 0.f);
        if (F32OUT) {
          of[row * SOUT + col] = v;
        } else {
          unsigned hu = bf16rne(v);
          oh[row * SOUT + col] = (unsigned short)hu;
          float lo = v - __uint_as_float(hu << 16);
          ol[row * SOUT + col] = (unsigned short)bf16rne(lo);
        }
      }
    }
  }
}

__global__ __launch_bounds__(256, 2) void head_kernel(
    const float* __restrict__ h,
    const int* __restrict__ src, const int* __restrict__ dst,
    const float* __restrict__ ef,
    const unsigned short* __restrict__ WTh1, const unsigned short* __restrict__ WTl1,
    const unsigned short* __restrict__ WTh2, const unsigned short* __restrict__ WTl2,
    const unsigned short* __restrict__ WTh3, const unsigned short* __restrict__ WTl3,
    const float* __restrict__ b1, const float* __restrict__ b2,
    const float* __restrict__ b3,
    const float* __restrict__ W4, const float* __restrict__ b4,
    float* __restrict__ out) {
  __shared__ __align__(16) unsigned short bufA[2 * 32 * 168]; // pair planes / z2 planes
  __shared__ __align__(16) unsigned short bufB[2 * 32 * 264]; // z1 planes / z3 f32
  const int t = threadIdx.x;
  const int e0 = blockIdx.x * TE;
  const int w = t >> 6, l = t & 63;

  unsigned short* PH  = bufA;              // [32][168]
  unsigned short* PL  = bufA + 32 * 168;
  unsigned short* Z1H = bufB;              // [32][264]
  unsigned short* Z1L = bufB + 32 * 264;
  unsigned short* Z2H = bufA;              // [32][136]
  unsigned short* Z2L = bufA + 32 * 136;
  float* Z3 = (float*)bufB;                // [32][68]

  { // gather pair rows, split to bf16 hi/lo planes; cols [144,160) zero-pad
    int el = t & 31, q = t >> 5;
    int e = e0 + el;
    int s = src[e], d = dst[e];
    #pragma unroll
    for (int p5 = 0; p5 < 5; ++p5) {
      int qq = q + p5 * 8;
      float4 v = {0.f, 0.f, 0.f, 0.f};
      if (qq < 16)      v = ((const float4*)(h + (size_t)s * ND))[qq];
      else if (qq < 32) v = ((const float4*)(h + (size_t)d * ND))[qq - 16];
      else if (qq < 36) v = ((const float4*)(ef + (size_t)e * ED))[qq - 32];
      unsigned h0 = bf16rne(v.x), h1 = bf16rne(v.y),
               h2 = bf16rne(v.z), h3 = bf16rne(v.w);
      ushort4v hv = {(unsigned short)h0, (unsigned short)h1,
                     (unsigned short)h2, (unsigned short)h3};
      ushort4v lv = {(unsigned short)bf16rne(v.x - __uint_as_float(h0 << 16)),
                     (unsigned short)bf16rne(v.y - __uint_as_float(h1 << 16)),
                     (unsigned short)bf16rne(v.z - __uint_as_float(h2 << 16)),
                     (unsigned short)bf16rne(v.w - __uint_as_float(h3 << 16))};
      *(ushort4v*)(PH + el * 168 + qq * 4) = hv;
      *(ushort4v*)(PL + el * 168 + qq * 4) = lv;
    }
  }
  __syncthreads();
  mfma_layer<160, 256, 168, 264, 4, false>(PH, PL, Z1H, Z1L, nullptr,
                                           WTh1, WTl1, b1, w, l);
  __syncthreads();
  mfma_layer<256, 128, 264, 136, 2, false>(Z1H, Z1L, Z2H, Z2L, nullptr,
                                           WTh2, WTl2, b2, w, l);
  __syncthreads();
  mfma_layer<128, 64, 136, 68, 1, true>(Z2H, Z2L, nullptr, nullptr, Z3,
                                        WTh3, WTl3, b3, w, l);
  __syncthreads();
  if (t < TE) {
    const float* zr = Z3 + t * 68;
    float acc = b4[0];
    #pragma unroll
    for (int q = 0; q < 16; ++q) {
      float4 z  = *(const float4*)(zr + q * 4);
      float4 wv = *(const float4*)(W4 + q * 4);
      acc = fmaf(z.x, wv.x, acc); acc = fmaf(z.y, wv.y, acc);
      acc = fmaf(z.z, wv.z, acc); acc = fmaf(z.w, wv.w, acc);
    }
    out[e0 + t] = acc;
  }
}

// ================= launch =================

extern "C" void kernel_launch(void* const* d_in, const int* in_sizes, int n_in,
                              void* d_out, int out_size, void* d_ws, size_t ws_size,
                              hipStream_t stream) {
  const float* x  = (const float*)d_in[0];
  const int*   ei = (const int*)d_in[1];
  const float* ef = (const float*)d_in[2];
  const float* cW = (const float*)d_in[4];
  const float* cb = (const float*)d_in[5];
  const float* W1 = (const float*)d_in[6];
  const float* b1 = (const float*)d_in[7];
  const float* W2 = (const float*)d_in[8];
  const float* b2 = (const float*)d_in[9];
  const float* W3 = (const float*)d_in[10];
  const float* b3 = (const float*)d_in[11];
  const float* W4 = (const float*)d_in[12];
  const float* b4 = (const float*)d_in[13];
  float* outp = (float*)d_out;

  const int* src = ei;
  const int* dst = ei + NE;

  float* h_a  = (float*)d_ws;                     // [NN][64]
  float* h_b  = h_a + (size_t)NN * ND;            // [NN][64]
  float* agg  = h_b + (size_t)NN * ND;            // [NN][80]
  int*   dcnt = (int*)(agg + (size_t)NN * AGGD);  // [NN]
  int*   base = dcnt + NN;                        // [NN]
  int*   fill = base + NN;                        // [NN]
  int*   sidx = fill + NN;                        // [NE]
  int*   eidx = sidx + NE;                        // [NE]
  unsigned short* WTh1 =
      (unsigned short*)(((uintptr_t)(eidx + NE) + 63) & ~(uintptr_t)63);
  unsigned short* WTl1 = WTh1 + 160 * 256;        // 40960 each
  unsigned short* WTh2 = WTl1 + 160 * 256;
  unsigned short* WTl2 = WTh2 + 256 * 128;        // 32768 each
  unsigned short* WTh3 = WTl2 + 256 * 128;
  unsigned short* WTl3 = WTh3 + 128 * 64;         // 8192 each

  // ---- weight prep (hi / lo bf16, MFMA-tiled) ----
  prep_kernel<144, 160, 256, false><<<160, 256, 0, stream>>>(W1, WTh1);
  prep_kernel<144, 160, 256, true ><<<160, 256, 0, stream>>>(W1, WTl1);
  prep_kernel<256, 256, 128, false><<<128, 256, 0, stream>>>(W2, WTh2);
  prep_kernel<256, 256, 128, true ><<<128, 256, 0, stream>>>(W2, WTl2);
  prep_kernel<128, 128,  64, false><<< 32, 256, 0, stream>>>(W3, WTh3);
  prep_kernel<128, 128,  64, true ><<< 32, 256, 0, stream>>>(W3, WTl3);

  // ---- CSR build (once; reused both layers) ----
  hipMemsetAsync(dcnt, 0, NN * sizeof(int), stream);
  hipMemsetAsync(fill, 0, NN * sizeof(int), stream);
  count_kernel<<<(NE + 255) / 256, 256, 0, stream>>>(dst, dcnt);
  scan_kernel<<<1, 1024, 0, stream>>>(dcnt, base);
  place_kernel<<<(NE + 255) / 256, 256, 0, stream>>>(src, dst, base, fill, sidx, eidx);

  // ---- layer 1 (input x) ----
  gather_kernel<true><<<NN / 4, 256, 0, stream>>>(x, sidx, eidx, ef, base, dcnt, agg);
  node_kernel<<<NN / 4, 256, 0, stream>>>(x, agg, dcnt, cW, cb, h_a);

  // ---- layer 2 (input h_a); ef columns of agg persist ----
  gather_kernel<false><<<NN / 4, 256, 0, stream>>>(h_a, sidx, eidx, ef, base, dcnt, agg);
  node_kernel<<<NN / 4, 256, 0, stream>>>(h_a, agg, dcnt, cW, cb, h_b);

  // ---- edge head (MFMA, dedup'd weight streams) ----
  head_kernel<<<NE / TE, 256, 0, stream>>>(h_b, src, dst, ef,
                                           WTh1, WTl1, WTh2, WTl2, WTh3, WTl3,
                                           b1, b2, b3, W4, b4, outp);
}

// Round 14
// 891.734 us; speedup vs baseline: 6.1483x; 1.2050x over previous
//
#include <hip/hip_runtime.h>
#include <hip/hip_bf16.h>

#define ND 64
#define ED 16
#define NN 50000
#define NE 800000
#define CIN 144   // 2*ND+ED
#define AGGD 80   // ND+ED
#define TE 32     // edges per head block
#define NB 49     // scan blocks: ceil(NN/1024)

typedef __attribute__((ext_vector_type(8))) short short8;
typedef __attribute__((ext_vector_type(4))) float f32x4;
typedef __attribute__((ext_vector_type(4))) unsigned int uint4v;
typedef __attribute__((ext_vector_type(4))) unsigned short ushort4v;

union FragU { uint4v u; short8 s; };

__device__ __forceinline__ unsigned bf16rne(float v) {
  unsigned u = __float_as_uint(v);
  return (u + 0x7fffu + ((u >> 16) & 1u)) >> 16;
}
__device__ __forceinline__ unsigned pk_bf16(float a, float b) {
  __hip_bfloat162 h = __float22bfloat162_rn(float2{a, b});
  unsigned r; __builtin_memcpy(&r, &h, 4);
  return r;   // low16 = bf16(a), high16 = bf16(b)
}

// ================= graph pipeline =================

__global__ __launch_bounds__(256) void count_kernel(const int* __restrict__ dst,
                                                    int* __restrict__ dcnt) {
  int t = blockIdx.x * 256 + threadIdx.x;
  if (t < NE) atomicAdd(&dcnt[dst[t]], 1);
}

// scan1: per-1024-block exclusive scan + block sums (shuffle-based)
__global__ __launch_bounds__(1024) void scan1_kernel(const int* __restrict__ dcnt,
                                                     int* __restrict__ base,
                                                     int* __restrict__ bsum) {
  __shared__ int ws[16];
  int b = blockIdx.x, t = threadIdx.x;
  int i = b * 1024 + t;
  int v = (i < NN) ? dcnt[i] : 0;
  int x = v;
  int lane = t & 63;
  #pragma unroll
  for (int d = 1; d < 64; d <<= 1) {
    int y = __shfl_up(x, d, 64);
    if (lane >= d) x += y;
  }
  if (lane == 63) ws[t >> 6] = x;
  __syncthreads();
  if (t < 16) {
    int y = ws[t];
    #pragma unroll
    for (int d = 1; d < 16; d <<= 1) {
      int z = __shfl_up(y, d, 16);
      if (t >= d) y += z;
    }
    ws[t] = y;
  }
  __syncthreads();
  int woff = (t >= 64) ? ws[(t >> 6) - 1] : 0;
  int incl = x + woff;
  if (i < NN) base[i] = incl - v;
  if (t == 1023) bsum[b] = incl;
}

// scan2: exclusive scan of NB block sums (single wave)
__global__ __launch_bounds__(64) void scan2_kernel(int* __restrict__ bsum) {
  int t = threadIdx.x;
  int v = (t < NB) ? bsum[t] : 0;
  int x = v;
  #pragma unroll
  for (int d = 1; d < 64; d <<= 1) {
    int y = __shfl_up(x, d, 64);
    if (t >= d) x += y;
  }
  if (t < NB) bsum[t] = x - v;
}

// scan3: add block offsets
__global__ __launch_bounds__(256) void scan3_kernel(int* __restrict__ base,
                                                    const int* __restrict__ bsum) {
  int i = blockIdx.x * 256 + threadIdx.x;
  if (i < NN) base[i] += bsum[i >> 10];
}

__global__ __launch_bounds__(256) void place_kernel(const int* __restrict__ src,
                                                    const int* __restrict__ dst,
                                                    const int* __restrict__ base,
                                                    int* __restrict__ fill,
                                                    int* __restrict__ sidx,
                                                    int* __restrict__ eidx) {
  int e = blockIdx.x * 256 + threadIdx.x;
  if (e < NE) {
    int d = dst[e];
    int slot = base[d] + atomicAdd(&fill[d], 1);
    sidx[slot] = src[e];
    eidx[slot] = e;
  }
}

template<bool WITH_EF>
__global__ __launch_bounds__(256) void gather_kernel(const float* __restrict__ h,
                                                     const int* __restrict__ sidx,
                                                     const int* __restrict__ eidx,
                                                     const float* __restrict__ ef,
                                                     const int* __restrict__ base,
                                                     const int* __restrict__ dcnt,
                                                     float* __restrict__ agg) {
  int wid  = (blockIdx.x * 256 + threadIdx.x) >> 6;
  int lane = threadIdx.x & 63;
  if (wid >= NN) return;
  int b0 = base[wid], deg = dcnt[wid];
  float acc = 0.f;
  int k = 0;
  for (; k + 2 <= deg; k += 2) {
    int s0 = sidx[b0 + k], s1 = sidx[b0 + k + 1];
    float a = h[(size_t)s0 * ND + lane];
    float b = h[(size_t)s1 * ND + lane];
    acc += a + b;
  }
  if (k < deg) acc += h[(size_t)sidx[b0 + k] * ND + lane];
  agg[(size_t)wid * AGGD + lane] = acc;
  if (WITH_EF) {
    int sub = lane >> 4, f = lane & 15;
    float ae = 0.f;
    for (int kk = sub; kk < deg; kk += 4)
      ae += ef[(size_t)eidx[b0 + kk] * ED + f];
    ae += __shfl_down(ae, 32);
    ae += __shfl_down(ae, 16);
    if (lane < 16) agg[(size_t)wid * AGGD + ND + lane] = ae;
  }
}

__global__ __launch_bounds__(256) void node_kernel(const float* __restrict__ h,
                                                   const float* __restrict__ agg,
                                                   const int* __restrict__ dcnt,
                                                   const float* __restrict__ W,
                                                   const float* __restrict__ b,
                                                   float* __restrict__ hout) {
  __shared__ float in[4][CIN];
  int j  = threadIdx.x & 63;
  int nl = threadIdx.x >> 6;
  int n  = blockIdx.x * 4 + nl;
  float inv = 1.0f / fmaxf((float)dcnt[n], 1.0f);
  in[nl][j]      = h[(size_t)n * ND + j];
  in[nl][ND + j] = agg[(size_t)n * AGGD + j] * inv;
  if (j < ED) in[nl][2 * ND + j] = agg[(size_t)n * AGGD + ND + j] * inv;
  __syncthreads();
  float acc = b[j];
  #pragma unroll 4
  for (int i = 0; i < CIN; i++)
    acc = fmaf(in[nl][i], W[i * ND + j], acc);
  hout[(size_t)n * ND + j] = fmaxf(acc, 0.0f);
}

// ============ weight prep: Wh / Wl bf16, MFMA B-frag tiled ==========
// idx = (ct*KS + ks)*512 + lk*128 + lr*8 + i ; k = ks*32+lk*8+i, n = ct*16+lr.
template<int K, int KP, int NO, bool LO>
__device__ __forceinline__ void prep_body(const float* __restrict__ W,
                                          unsigned short* __restrict__ WT,
                                          int bx, int tx) {
  constexpr int KS = KP / 32;
  int idx = bx * 256 + tx;
  if (idx >= KP * NO) return;
  int i  = idx & 7;
  int lr = (idx >> 3) & 15;
  int lk = (idx >> 7) & 3;
  int rest = idx >> 9;
  int ks = rest % KS, ct = rest / KS;
  int k = ks * 32 + lk * 8 + i;
  int n = ct * 16 + lr;
  float wv = (k < K) ? W[k * NO + n] : 0.f;
  unsigned hi = bf16rne(wv);
  unsigned outb = hi;
  if (LO) {
    float lo = wv - __uint_as_float(hi << 16);
    outb = bf16rne(lo);
  }
  WT[idx] = (unsigned short)outb;
}

__global__ __launch_bounds__(256) void prep_all_kernel(
    const float* __restrict__ W1, const float* __restrict__ W2,
    const float* __restrict__ W3,
    unsigned short* __restrict__ WTh1, unsigned short* __restrict__ WTl1,
    unsigned short* __restrict__ WTh2, unsigned short* __restrict__ WTl2,
    unsigned short* __restrict__ WTh3, unsigned short* __restrict__ WTl3) {
  int bx = blockIdx.x, tx = threadIdx.x;
  if      (bx < 160) prep_body<144, 160, 256, false>(W1, WTh1, bx, tx);
  else if (bx < 320) prep_body<144, 160, 256, true >(W1, WTl1, bx - 160, tx);
  else if (bx < 448) prep_body<256, 256, 128, false>(W2, WTh2, bx - 320, tx);
  else if (bx < 576) prep_body<256, 256, 128, true >(W2, WTl2, bx - 448, tx);
  else if (bx < 608) prep_body<128, 128,  64, false>(W3, WTh3, bx - 576, tx);
  else               prep_body<128, 128,  64, true >(W3, WTl3, bx - 608, tx);
}

// ================= MFMA head =================
// Activations in LDS are frag-tiled bf16 planes:
//   addr = (rb*KS + ks)*512 + lk*128 + lr*8 + i ; row = rb*16+lr, k = ks*32+lk*8+i
// -> lane l reads its A-frag at base + (rb*KS+ks)*512 + l*8 (linear, conflict-free).
template<int KP, int NO, int CTW, int KSO, bool F32OUT>
__device__ __forceinline__ void mfma_layer(
    const unsigned short* __restrict__ zh, const unsigned short* __restrict__ zl,
    unsigned short* __restrict__ oh, unsigned short* __restrict__ ol,
    float* __restrict__ of,
    const unsigned short* __restrict__ WTh, const unsigned short* __restrict__ WTl,
    const float* __restrict__ bias, int w, int l) {
  constexpr int KS = KP / 32;
  const int lr = l & 15, lk = l >> 4;
  const int ct0 = w * CTW;
  const unsigned short* ah = zh + l * 8;
  const unsigned short* al = zl + l * 8;
  const unsigned short* wth = WTh + (size_t)(ct0 * KS) * 512 + l * 8;
  const unsigned short* wtl = WTl + (size_t)(ct0 * KS) * 512 + l * 8;

  f32x4 acc[CTW][2];
  #pragma unroll
  for (int j = 0; j < CTW; ++j) {
    float bb = bias[(ct0 + j) * 16 + lr];
    acc[j][0] = f32x4{bb, bb, bb, bb};
    acc[j][1] = f32x4{bb, bb, bb, bb};
  }

  FragU whf[CTW], wlf[CTW], nwh[CTW], nwl[CTW];
  #pragma unroll
  for (int j = 0; j < CTW; ++j) {
    whf[j].u = *(const uint4v*)(wth + j * KS * 512);
    wlf[j].u = *(const uint4v*)(wtl + j * KS * 512);
  }

  #pragma unroll
  for (int ks = 0; ks < KS; ++ks) {
    FragU A0h, A1h, A0l, A1l;
    A0h.s = *(const short8*)(ah + ks * 512);
    A1h.s = *(const short8*)(ah + (KS + ks) * 512);
    A0l.s = *(const short8*)(al + ks * 512);
    A1l.s = *(const short8*)(al + (KS + ks) * 512);
    if (ks + 1 < KS) {
      #pragma unroll
      for (int j = 0; j < CTW; ++j) {
        nwh[j].u = *(const uint4v*)(wth + (j * KS + ks + 1) * 512);
        nwl[j].u = *(const uint4v*)(wtl + (j * KS + ks + 1) * 512);
      }
    }
    #pragma unroll
    for (int j = 0; j < CTW; ++j) {
      acc[j][0] = __builtin_amdgcn_mfma_f32_16x16x32_bf16(A0h.s, whf[j].s, acc[j][0], 0, 0, 0);
      acc[j][1] = __builtin_amdgcn_mfma_f32_16x16x32_bf16(A1h.s, whf[j].s, acc[j][1], 0, 0, 0);
      acc[j][0] = __builtin_amdgcn_mfma_f32_16x16x32_bf16(A0l.s, whf[j].s, acc[j][0], 0, 0, 0);
      acc[j][1] = __builtin_amdgcn_mfma_f32_16x16x32_bf16(A1l.s, whf[j].s, acc[j][1], 0, 0, 0);
      acc[j][0] = __builtin_amdgcn_mfma_f32_16x16x32_bf16(A0h.s, wlf[j].s, acc[j][0], 0, 0, 0);
      acc[j][1] = __builtin_amdgcn_mfma_f32_16x16x32_bf16(A1h.s, wlf[j].s, acc[j][1], 0, 0, 0);
    }
    if (ks + 1 < KS) {
      #pragma unroll
      for (int j = 0; j < CTW; ++j) { whf[j] = nwh[j]; wlf[j] = nwl[j]; }
    }
  }

  // C layout (m89): col = lane&15 (-> lr), row = (lane>>4)*4 + q (+ rb*16)
  #pragma unroll
  for (int j = 0; j < CTW; ++j) {
    const int col0 = (ct0 + j) * 16 + lr;
    #pragma unroll
    for (int rb = 0; rb < 2; ++rb) {
      float v0 = fmaxf(acc[j][rb][0], 0.f);
      float v1 = fmaxf(acc[j][rb][1], 0.f);
      float v2 = fmaxf(acc[j][rb][2], 0.f);
      float v3 = fmaxf(acc[j][rb][3], 0.f);
      if (F32OUT) {
        const int r0 = rb * 16 + lk * 4;
        of[(r0 + 0) * 68 + col0] = v0;
        of[(r0 + 1) * 68 + col0] = v1;
        of[(r0 + 2) * 68 + col0] = v2;
        of[(r0 + 3) * 68 + col0] = v3;
      } else {
        unsigned uh01 = pk_bf16(v0, v1), uh23 = pk_bf16(v2, v3);
        unsigned ul01 = pk_bf16(v0 - __uint_as_float(uh01 << 16),
                                v1 - __uint_as_float(uh01 & 0xffff0000u));
        unsigned ul23 = pk_bf16(v2 - __uint_as_float(uh23 << 16),
                                v3 - __uint_as_float(uh23 & 0xffff0000u));
        const int o = (rb * KSO + (col0 >> 5)) * 512 +
                      ((col0 & 31) >> 3) * 128 + lk * 32 + (col0 & 7);
        oh[o]      = (unsigned short)(uh01 & 0xffffu);
        oh[o + 8]  = (unsigned short)(uh01 >> 16);
        oh[o + 16] = (unsigned short)(uh23 & 0xffffu);
        oh[o + 24] = (unsigned short)(uh23 >> 16);
        ol[o]      = (unsigned short)(ul01 & 0xffffu);
        ol[o + 8]  = (unsigned short)(ul01 >> 16);
        ol[o + 16] = (unsigned short)(ul23 & 0xffffu);
        ol[o + 24] = (unsigned short)(ul23 >> 16);
      }
    }
  }
}

__global__ __launch_bounds__(256, 3) void head_kernel(
    const float* __restrict__ h,
    const int* __restrict__ src, const int* __restrict__ dst,
    const float* __restrict__ ef,
    const unsigned short* __restrict__ WTh1, const unsigned short* __restrict__ WTl1,
    const unsigned short* __restrict__ WTh2, const unsigned short* __restrict__ WTl2,
    const unsigned short* __restrict__ WTh3, const unsigned short* __restrict__ WTl3,
    const float* __restrict__ b1, const float* __restrict__ b2,
    const float* __restrict__ b3,
    const float* __restrict__ W4, const float* __restrict__ b4,
    float* __restrict__ out) {
  // 53248 B total; overlays: z2 over dead pair, z3 over dead z1-head.
  __shared__ __align__(16) unsigned short S[26624];
  unsigned short* PH  = S;            // pair hi: 2*5*512 = 5120
  unsigned short* PL  = S + 5120;     // pair lo
  unsigned short* Z1H = S + 10240;    // z1 hi: 2*8*512 = 8192
  unsigned short* Z1L = S + 18432;    // z1 lo
  unsigned short* Z2H = S;            // z2 hi: 2*4*512 = 4096 (over pair)
  unsigned short* Z2L = S + 4096;     // z2 lo
  float*          Z3  = (float*)(S + 8192);  // [32][68] f32 (over z1 head)

  const int t = threadIdx.x;
  const int e0 = blockIdx.x * TE;
  const int w = t >> 6, l = t & 63;

  { // gather pair -> frag-tiled hi/lo planes; k in [144,160) zero-padded
    int el = t & 31, q8 = t >> 5;
    int rb = el >> 4, lra = el & 15;
    int e = e0 + el;
    int s = src[e], d = dst[e];
    #pragma unroll
    for (int p5 = 0; p5 < 5; ++p5) {
      int qq = q8 + p5 * 8;            // float4 index over 160 k-values
      float4 v = {0.f, 0.f, 0.f, 0.f};
      if (qq < 16)      v = ((const float4*)(h + (size_t)s * ND))[qq];
      else if (qq < 32) v = ((const float4*)(h + (size_t)d * ND))[qq - 16];
      else if (qq < 36) v = ((const float4*)(ef + (size_t)e * ED))[qq - 32];
      unsigned uh01 = pk_bf16(v.x, v.y), uh23 = pk_bf16(v.z, v.w);
      unsigned ul01 = pk_bf16(v.x - __uint_as_float(uh01 << 16),
                              v.y - __uint_as_float(uh01 & 0xffff0000u));
      unsigned ul23 = pk_bf16(v.z - __uint_as_float(uh23 << 16),
                              v.w - __uint_as_float(uh23 & 0xffff0000u));
      int idx = (rb * 5 + (qq >> 3)) * 512 + ((qq & 7) >> 1) * 128 +
                lra * 8 + (qq & 1) * 4;
      *(ushort4v*)(PH + idx) = ushort4v{(unsigned short)(uh01 & 0xffffu),
                                        (unsigned short)(uh01 >> 16),
                                        (unsigned short)(uh23 & 0xffffu),
                                        (unsigned short)(uh23 >> 16)};
      *(ushort4v*)(PL + idx) = ushort4v{(unsigned short)(ul01 & 0xffffu),
                                        (unsigned short)(ul01 >> 16),
                                        (unsigned short)(ul23 & 0xffffu),
                                        (unsigned short)(ul23 >> 16)};
    }
  }
  __syncthreads();
  mfma_layer<160, 256, 4, 8, false>(PH, PL, Z1H, Z1L, nullptr, WTh1, WTl1, b1, w, l);
  __syncthreads();
  mfma_layer<256, 128, 2, 4, false>(Z1H, Z1L, Z2H, Z2L, nullptr, WTh2, WTl2, b2, w, l);
  __syncthreads();
  mfma_layer<128, 64, 1, 1, true>(Z2H, Z2L, nullptr, nullptr, Z3, WTh3, WTl3, b3, w, l);
  __syncthreads();
  if (t < TE) {
    const float* zr = Z3 + t * 68;
    float acc = b4[0];
    #pragma unroll
    for (int q = 0; q < 16; ++q) {
      float4 z  = *(const float4*)(zr + q * 4);
      float4 wv = *(const float4*)(W4 + q * 4);
      acc = fmaf(z.x, wv.x, acc); acc = fmaf(z.y, wv.y, acc);
      acc = fmaf(z.z, wv.z, acc); acc = fmaf(z.w, wv.w, acc);
    }
    out[e0 + t] = acc;
  }
}

// ================= launch =================

extern "C" void kernel_launch(void* const* d_in, const int* in_sizes, int n_in,
                              void* d_out, int out_size, void* d_ws, size_t ws_size,
                              hipStream_t stream) {
  const float* x  = (const float*)d_in[0];
  const int*   ei = (const int*)d_in[1];
  const float* ef = (const float*)d_in[2];
  const float* cW = (const float*)d_in[4];
  const float* cb = (const float*)d_in[5];
  const float* W1 = (const float*)d_in[6];
  const float* b1 = (const float*)d_in[7];
  const float* W2 = (const float*)d_in[8];
  const float* b2 = (const float*)d_in[9];
  const float* W3 = (const float*)d_in[10];
  const float* b3 = (const float*)d_in[11];
  const float* W4 = (const float*)d_in[12];
  const float* b4 = (const float*)d_in[13];
  float* outp = (float*)d_out;

  const int* src = ei;
  const int* dst = ei + NE;

  float* h_a  = (float*)d_ws;                     // [NN][64]
  float* h_b  = h_a + (size_t)NN * ND;            // [NN][64]
  float* agg  = h_b + (size_t)NN * ND;            // [NN][80]
  int*   dcnt = (int*)(agg + (size_t)NN * AGGD);  // [NN]
  int*   base = dcnt + NN;                        // [NN]
  int*   fill = base + NN;                        // [NN]
  int*   sidx = fill + NN;                        // [NE]
  int*   eidx = sidx + NE;                        // [NE]
  int*   bsum = eidx + NE;                        // [NB]
  unsigned short* WTh1 =
      (unsigned short*)(((uintptr_t)(bsum + NB) + 63) & ~(uintptr_t)63);
  unsigned short* WTl1 = WTh1 + 160 * 256;
  unsigned short* WTh2 = WTl1 + 160 * 256;
  unsigned short* WTl2 = WTh2 + 256 * 128;
  unsigned short* WTh3 = WTl2 + 256 * 128;
  unsigned short* WTl3 = WTh3 + 128 * 64;

  // ---- weight prep (one kernel: all six hi/lo tiled arrays) ----
  prep_all_kernel<<<640, 256, 0, stream>>>(W1, W2, W3, WTh1, WTl1,
                                           WTh2, WTl2, WTh3, WTl3);

  // ---- CSR build ----
  hipMemsetAsync(dcnt, 0, NN * sizeof(int), stream);
  hipMemsetAsync(fill, 0, NN * sizeof(int), stream);
  count_kernel<<<(NE + 255) / 256, 256, 0, stream>>>(dst, dcnt);
  scan1_kernel<<<NB, 1024, 0, stream>>>(dcnt, base, bsum);
  scan2_kernel<<<1, 64, 0, stream>>>(bsum);
  scan3_kernel<<<(NN + 255) / 256, 256, 0, stream>>>(base, bsum);
  place_kernel<<<(NE + 255) / 256, 256, 0, stream>>>(src, dst, base, fill, sidx, eidx);

  // ---- layer 1 (input x) ----
  gather_kernel<true><<<NN / 4, 256, 0, stream>>>(x, sidx, eidx, ef, base, dcnt, agg);
  node_kernel<<<NN / 4, 256, 0, stream>>>(x, agg, dcnt, cW, cb, h_a);

  // ---- layer 2 (input h_a); ef columns of agg persist ----
  gather_kernel<false><<<NN / 4, 256, 0, stream>>>(h_a, sidx, eidx, ef, base, dcnt, agg);
  node_kernel<<<NN / 4, 256, 0, stream>>>(h_a, agg, dcnt, cW, cb, h_b);

  // ---- edge head (MFMA, frag-tiled activations) ----
  head_kernel<<<NE / TE, 256, 0, stream>>>(h_b, src, dst, ef,
                                           WTh1, WTl1, WTh2, WTl2, WTh3, WTl3,
                                           b1, b2, b3, W4, b4, outp);
}